// Round 5
// baseline (817.269 us; speedup 1.0000x reference)
//
#include <hip/hip_runtime.h>
#include <math.h>

#define N_NODES 50000
#define N_EDGES 800000
#define SCAN_NB ((N_NODES + 255) / 256)   // 196
#define VOCAB   30000

typedef __attribute__((ext_vector_type(8))) short bf16x8;
typedef __attribute__((ext_vector_type(4))) float f32x4;

__device__ inline short f2bf(float f) {
    union { float f; unsigned u; } v; v.f = f;
    unsigned r = v.u + 0x7FFFu + ((v.u >> 16) & 1u);   // RNE
    return (short)(r >> 16);
}

__device__ inline float fsig(float x)  { return __builtin_amdgcn_rcpf(1.0f + __expf(-x)); }
__device__ inline float ftanh(float x) { float t = __expf(2.0f * x); return 1.0f - 2.0f * __builtin_amdgcn_rcpf(t + 1.0f); }

__device__ inline f32x4 mfma16(bf16x8 a, bf16x8 b, f32x4 c) {
    return __builtin_amdgcn_mfma_f32_16x16x32_bf16(a, b, c, 0, 0, 0);
}

// ================================================================ embed -> bf16 table
__global__ void k_embcvt(const float* __restrict__ e, short* __restrict__ o) {
    int i = blockIdx.x * 256 + threadIdx.x;   // 8 elems per thread
    if (i >= VOCAB * 64 / 8) return;
    const float4* p = (const float4*)(e + i * 8);
    float4 a = p[0], b = p[1];
    bf16x8 v;
    v[0]=f2bf(a.x); v[1]=f2bf(a.y); v[2]=f2bf(a.z); v[3]=f2bf(a.w);
    v[4]=f2bf(b.x); v[5]=f2bf(b.y); v[6]=f2bf(b.z); v[7]=f2bf(b.w);
    *(bf16x8*)(o + i * 8) = v;
}

// ================================================================ CSR build
__global__ void k_count(const int* __restrict__ ei, int* __restrict__ cnt) {
    int e = blockIdx.x * 256 + threadIdx.x;
    if (e < N_EDGES) atomicAdd(&cnt[ei[N_EDGES + e]], 1);
}

__global__ void k_scan_local(const int* __restrict__ cnt, int* __restrict__ excl,
                             int* __restrict__ bsum) {
    __shared__ int s[256];
    int tid = threadIdx.x;
    int i = blockIdx.x * 256 + tid;
    int v = (i < N_NODES) ? cnt[i] : 0;
    s[tid] = v;
    __syncthreads();
    #pragma unroll
    for (int off = 1; off < 256; off <<= 1) {
        int t = (tid >= off) ? s[tid - off] : 0;
        __syncthreads();
        s[tid] += t;
        __syncthreads();
    }
    if (i < N_NODES) excl[i] = s[tid] - v;
    if (tid == 255) bsum[blockIdx.x] = s[255];
}

__global__ void k_scan_bsum(int* __restrict__ bsum) {
    __shared__ int s[256];
    int tid = threadIdx.x;
    int v = (tid < SCAN_NB) ? bsum[tid] : 0;
    s[tid] = v;
    __syncthreads();
    #pragma unroll
    for (int off = 1; off < 256; off <<= 1) {
        int t = (tid >= off) ? s[tid - off] : 0;
        __syncthreads();
        s[tid] += t;
        __syncthreads();
    }
    if (tid < SCAN_NB) bsum[tid] = s[tid] - v;
}

__global__ void k_make_starts(const int* __restrict__ excl, const int* __restrict__ bsum,
                              const int* __restrict__ cnt,
                              int* __restrict__ starts, int* __restrict__ cursor,
                              float* __restrict__ dinv) {
    int i = blockIdx.x * 256 + threadIdx.x;
    if (i >= N_NODES) return;
    int st = excl[i] + bsum[blockIdx.x];
    starts[i] = st;
    cursor[i] = st;
    dinv[i] = rsqrtf((float)cnt[i] + 1.0f);
}

__global__ void k_fill(const int* __restrict__ ei, int* __restrict__ cursor,
                       int* __restrict__ csr_src) {
    int e = blockIdx.x * 256 + threadIdx.x;
    if (e >= N_EDGES) return;
    int c = ei[N_EDGES + e];
    int p = atomicAdd(&cursor[c], 1);
    csr_src[p] = ei[e];
}

// ================================================================ GRU via MFMA
// 1024-thread block = 16 waves sharing one 48KB weight stage; each wave owns
// ONE 16-node tile (tile = wave*gridDim + blockIdx) -> no multi-tile tail.
__global__ __launch_bounds__(1024) void k_gru_mfma(
    const int*   __restrict__ xtext,
    const short* __restrict__ embbf,   // [VOCAB,64] bf16
    const float* __restrict__ w_ih, const float* __restrict__ w_hh,
    const float* __restrict__ b_ih, const float* __restrict__ b_hh,
    float* __restrict__ ht)            // [N,64]
{
    __shared__ short bfrag[2 * 2 * 12 * 64 * 8];   // 48KB
    __shared__ short hbuf[16][16 * 64];            // 32KB

    const int tid = threadIdx.x;
    for (int u = tid; u < 3072; u += 1024) {
        int l   = u & 63;
        int ct  = (u >> 6) % 12;
        int ks  = (u / 768) & 1;
        int mat = u / 1536;
        const float* W = mat ? w_hh : w_ih;
        int c  = ct * 16 + (l & 15);
        int kb = ks * 32 + ((l >> 4) << 3);
        short* dst = &bfrag[u * 8];
        #pragma unroll
        for (int i = 0; i < 8; ++i) dst[i] = f2bf(W[c * 64 + kb + i]);
    }
    __syncthreads();

    const int lane = tid & 63;
    const int wave = tid >> 6;
    const int lg = lane >> 4;
    const int ll = lane & 15;

    const int tile = wave * gridDim.x + blockIdx.x;
    if (tile >= N_NODES / 16) return;
    const int nbase = tile * 16;
    const int nrow  = nbase + ll;

    // biases: r/z combined (ih+hh), n kept split
    float brz[8], bni[4], bnh[4];
    #pragma unroll
    for (int ct = 0; ct < 8; ++ct) brz[ct] = b_ih[ct * 16 + ll] + b_hh[ct * 16 + ll];
    #pragma unroll
    for (int j = 0; j < 4; ++j) {
        bni[j] = b_ih[128 + j * 16 + ll];
        bnh[j] = b_hh[128 + j * 16 + ll];
    }

    const bf16x8* BIH = (const bf16x8*)&bfrag[0];
    const bf16x8* BHH = (const bf16x8*)&bfrag[12288];
    short* hl = &hbuf[wave][0];

    float h_reg[4][4];
    #pragma unroll
    for (int ct = 0; ct < 4; ++ct)
        #pragma unroll
        for (int q = 0; q < 4; ++q) h_reg[ct][q] = 0.0f;

    bf16x8 eA0, eA1;
    {
        int tok = xtext[nrow * 16 + 0];
        const short* er = embbf + tok * 64;
        eA0 = *(const bf16x8*)(er + 8 * lg);
        eA1 = *(const bf16x8*)(er + 32 + 8 * lg);
    }

    for (int t = 0; t < 16; ++t) {
        f32x4 arz[8], ani[4], anh[4];
        #pragma unroll
        for (int ct = 0; ct < 8; ++ct) arz[ct] = (f32x4){brz[ct], brz[ct], brz[ct], brz[ct]};
        #pragma unroll
        for (int j = 0; j < 4; ++j) {
            ani[j] = (f32x4){bni[j], bni[j], bni[j], bni[j]};
            anh[j] = (f32x4){bnh[j], bnh[j], bnh[j], bnh[j]};
        }

        // prefetch next-step embedding (bf16, 2x16B)
        bf16x8 eN0, eN1;
        if (t < 15) {
            int tok = xtext[nrow * 16 + t + 1];
            const short* er = embbf + tok * 64;
            eN0 = *(const bf16x8*)(er + 8 * lg);
            eN1 = *(const bf16x8*)(er + 32 + 8 * lg);
        }

        // Gi
        #pragma unroll
        for (int ct = 0; ct < 8; ++ct) {
            arz[ct] = mfma16(eA0, BIH[ct * 64 + lane], arz[ct]);
            arz[ct] = mfma16(eA1, BIH[(12 + ct) * 64 + lane], arz[ct]);
        }
        #pragma unroll
        for (int j = 0; j < 4; ++j) {
            ani[j] = mfma16(eA0, BIH[(8 + j) * 64 + lane], ani[j]);
            ani[j] = mfma16(eA1, BIH[(20 + j) * 64 + lane], ani[j]);
        }

        // Gh
        if (t > 0) {
            #pragma unroll
            for (int ks = 0; ks < 2; ++ks) {
                int soct = (ks * 4 + lg) ^ (ll & 7);
                bf16x8 hA = *(const bf16x8*)&hl[ll * 64 + soct * 8];
                #pragma unroll
                for (int ct = 0; ct < 8; ++ct)
                    arz[ct] = mfma16(hA, BHH[(ks * 12 + ct) * 64 + lane], arz[ct]);
                #pragma unroll
                for (int j = 0; j < 4; ++j)
                    anh[j] = mfma16(hA, BHH[(ks * 12 + 8 + j) * 64 + lane], anh[j]);
            }
        }

        // gates + write transposed h (bf16, XOR-swizzled 16B octs)
        #pragma unroll
        for (int ct = 0; ct < 4; ++ct) {
            #pragma unroll
            for (int q = 0; q < 4; ++q) {
                float r  = fsig(arz[ct][q]);
                float z  = fsig(arz[ct + 4][q]);
                float nn = ftanh(ani[ct][q] + r * anh[ct][q]);
                float hn = (1.0f - z) * nn + z * h_reg[ct][q];
                h_reg[ct][q] = hn;
                int row = 4 * lg + q;
                int d   = ct * 16 + ll;
                int soct = (d >> 3) ^ (row & 7);
                hl[row * 64 + soct * 8 + (d & 7)] = f2bf(hn);
            }
        }

        eA0 = eN0; eA1 = eN1;
    }

    #pragma unroll
    for (int ct = 0; ct < 4; ++ct)
        #pragma unroll
        for (int q = 0; q < 4; ++q)
            ht[(nbase + 4 * lg + q) * 64 + ct * 16 + ll] = h_reg[ct][q];
}

// ================================================================ dense ms = dinv*( [x|ht] @ W1 )
__global__ void k_mm1(const float* __restrict__ x, const float* __restrict__ ht,
                      const float* __restrict__ W, const float* __restrict__ dinv,
                      float* __restrict__ M) {
    __shared__ float Wl[72 * 64];
    int tid = threadIdx.x;
    for (int i = tid; i < 72 * 64; i += 256) Wl[i] = W[i];
    __syncthreads();
    int j = tid & 63;
    int n = blockIdx.x * 4 + (tid >> 6);
    if (n >= N_NODES) return;
    float acc = 0.0f;
    const float* xr = x + n * 8;
    #pragma unroll
    for (int k = 0; k < 8; ++k) acc += xr[k] * Wl[k * 64 + j];
    const float* hr = ht + n * 64;
    #pragma unroll
    for (int k = 0; k < 64; ++k) acc += hr[k] * Wl[(8 + k) * 64 + j];
    M[n * 64 + j] = dinv[n] * acc;
}

// ================================================================ dense ms = dinv*(X @ W)  (K=64)
__global__ void k_mm64(const float* __restrict__ X, const float* __restrict__ W,
                       const float* __restrict__ dinv, float* __restrict__ M) {
    __shared__ float Wl[64 * 64];
    int tid = threadIdx.x;
    for (int i = tid; i < 64 * 64; i += 256) Wl[i] = W[i];
    __syncthreads();
    int j = tid & 63;
    int n = blockIdx.x * 4 + (tid >> 6);
    if (n >= N_NODES) return;
    const float* xr = X + n * 64;
    float acc = 0.0f;
    #pragma unroll
    for (int k = 0; k < 64; ++k) acc += xr[k] * Wl[k * 64 + j];
    M[n * 64 + j] = dinv[n] * acc;
}

// ================================================================ gather + self + bias + relu
__global__ __launch_bounds__(256) void k_gather(
    const float* __restrict__ ms, const int* __restrict__ csr_src,
    const int* __restrict__ starts, const int* __restrict__ cnt,
    const float* __restrict__ dinv, const float* __restrict__ b,
    float* __restrict__ out)
{
    int n = blockIdx.x * 4 + (threadIdx.x >> 6);
    if (n >= N_NODES) return;
    int j = threadIdx.x & 63;
    int c = cnt[n];
    const int* lst = csr_src + starts[n];
    float acc = ms[n * 64 + j];   // self-loop term
    int k = 0;
    for (; k + 8 <= c; k += 8) {
        int r[8];
        #pragma unroll
        for (int u = 0; u < 8; ++u) r[u] = lst[k + u];
        #pragma unroll
        for (int u = 0; u < 8; ++u) acc += ms[r[u] * 64 + j];
    }
    for (; k < c; ++k) acc += ms[lst[k] * 64 + j];
    float v = dinv[n] * acc + b[j];
    out[n * 64 + j] = fmaxf(v, 0.0f);
}

// ================================================================ edge classifier via MFMA
__global__ __launch_bounds__(256) void k_edge_mfma(
    const int* __restrict__ ei, const float* __restrict__ h,
    const float* __restrict__ Wl1, const float* __restrict__ bl1,
    const float* __restrict__ Wf,  const float* __restrict__ bf,
    float* __restrict__ out)
{
    __shared__ float wl_s[128 * 64];
    const int tid = threadIdx.x;
    for (int i = tid; i < 128 * 64; i += 256) wl_s[i] = Wl1[i];
    __syncthreads();

    const int lane = tid & 63;
    const int wave = tid >> 6;
    const int lg = lane >> 4;
    const int ll = lane & 15;

    bf16x8 B[16];
    #pragma unroll
    for (int ks = 0; ks < 4; ++ks) {
        #pragma unroll
        for (int ct = 0; ct < 4; ++ct) {
            int c  = ct * 16 + ll;
            int kb = ks * 32 + 8 * lg;
            bf16x8 v;
            #pragma unroll
            for (int i = 0; i < 8; ++i) v[i] = f2bf(wl_s[(kb + i) * 64 + c]);
            B[ks * 4 + ct] = v;
        }
    }
    float wf0[4], wf1[4], bl[4];
    #pragma unroll
    for (int ct = 0; ct < 4; ++ct) {
        int c = ct * 16 + ll;
        wf0[ct] = Wf[c * 2 + 0];
        wf1[ct] = Wf[c * 2 + 1];
        bl[ct]  = bl1[c];
    }
    const float bf0 = bf[0], bf1 = bf[1];

    for (int tile = blockIdx.x * 4 + wave; tile < N_EDGES / 16; tile += gridDim.x * 4) {
        const int ebase = tile * 16;
        const int erow  = ebase + ll;
        const int src = ei[erow];
        const int dst = ei[N_EDGES + erow];

        f32x4 acc[4];
        #pragma unroll
        for (int ct = 0; ct < 4; ++ct) acc[ct] = (f32x4){bl[ct], bl[ct], bl[ct], bl[ct]};

        #pragma unroll
        for (int ks = 0; ks < 4; ++ks) {
            const int node = (ks < 2) ? src : dst;
            const float4* p = (const float4*)&h[node * 64 + (ks & 1) * 32 + 8 * lg];
            float4 a4 = p[0], b4 = p[1];
            float fa[8] = {a4.x, a4.y, a4.z, a4.w, b4.x, b4.y, b4.z, b4.w};
            bf16x8 A;
            #pragma unroll
            for (int i = 0; i < 8; ++i) A[i] = f2bf(fa[i]);
            #pragma unroll
            for (int ct = 0; ct < 4; ++ct) acc[ct] = mfma16(A, B[ks * 4 + ct], acc[ct]);
        }

        float p0[4], p1[4];
        #pragma unroll
        for (int q = 0; q < 4; ++q) { p0[q] = 0.0f; p1[q] = 0.0f; }
        #pragma unroll
        for (int ct = 0; ct < 4; ++ct) {
            #pragma unroll
            for (int q = 0; q < 4; ++q) {
                float hd = fmaxf(acc[ct][q], 0.0f);
                p0[q] += hd * wf0[ct];
                p1[q] += hd * wf1[ct];
            }
        }
        #pragma unroll
        for (int m = 1; m <= 8; m <<= 1) {
            #pragma unroll
            for (int q = 0; q < 4; ++q) {
                p0[q] += __shfl_xor(p0[q], m, 64);
                p1[q] += __shfl_xor(p1[q], m, 64);
            }
        }
        if (ll < 8) {
            int q = ll >> 1, cls = ll & 1;
            float l0 = p0[q] + bf0, l1 = p1[q] + bf1;
            float mx  = fmaxf(l0, l1);
            float lse = mx + __logf(__expf(l0 - mx) + __expf(l1 - mx));
            float val = (cls ? l1 : l0) - lse;
            out[(ebase + 4 * lg + q) * 2 + cls] = val;
        }
    }
}

// ================================================================ launch
extern "C" void kernel_launch(void* const* d_in, const int* in_sizes, int n_in,
                              void* d_out, int out_size, void* d_ws, size_t ws_size,
                              hipStream_t stream) {
    const float* x     = (const float*)d_in[0];
    const int*   ei    = (const int*)  d_in[1];
    const int*   xtext = (const int*)  d_in[2];
    const float* embed = (const float*)d_in[3];
    const float* w_ih  = (const float*)d_in[4];
    const float* w_hh  = (const float*)d_in[5];
    const float* b_ih  = (const float*)d_in[6];
    const float* b_hh  = (const float*)d_in[7];
    const float* W1    = (const float*)d_in[8];
    const float* b1    = (const float*)d_in[9];
    const float* W2    = (const float*)d_in[10];
    const float* b2    = (const float*)d_in[11];
    const float* Wl1   = (const float*)d_in[12];
    const float* bl1   = (const float*)d_in[13];
    const float* Wf    = (const float*)d_in[14];
    const float* bf    = (const float*)d_in[15];
    float* out = (float*)d_out;

    char* ws = (char*)d_ws;
    size_t off = 0;
    auto alloc = [&](size_t bytes) { char* p = ws + off; off += (bytes + 255) & ~size_t(255); return p; };
    float* ht      = (float*)alloc(N_NODES * 64 * 4);
    float* ms      = (float*)alloc(N_NODES * 64 * 4);
    float* h1      = (float*)alloc(N_NODES * 64 * 4);
    float* h2      = (float*)alloc(N_NODES * 64 * 4);
    float* dinv    = (float*)alloc(N_NODES * 4);
    int*   cnt     = (int*)  alloc(N_NODES * 4);
    int*   excl    = (int*)  alloc(N_NODES * 4);
    int*   starts  = (int*)  alloc(N_NODES * 4);
    int*   cursor  = (int*)  alloc(N_NODES * 4);
    int*   bsum    = (int*)  alloc(SCAN_NB * 4);
    int*   csr_src = (int*)  alloc(N_EDGES * 4);
    short* embbf   = (short*)alloc(VOCAB * 64 * 2);

    // ---- bf16 embedding table
    k_embcvt<<<(VOCAB * 64 / 8 + 255) / 256, 256, 0, stream>>>(embed, embbf);

    // ---- CSR build (shared by both GCN layers)
    hipMemsetAsync(cnt, 0, N_NODES * 4, stream);
    k_count<<<(N_EDGES + 255) / 256, 256, 0, stream>>>(ei, cnt);
    k_scan_local<<<SCAN_NB, 256, 0, stream>>>(cnt, excl, bsum);
    k_scan_bsum<<<1, 256, 0, stream>>>(bsum);
    k_make_starts<<<SCAN_NB, 256, 0, stream>>>(excl, bsum, cnt, starts, cursor, dinv);
    k_fill<<<(N_EDGES + 255) / 256, 256, 0, stream>>>(ei, cursor, csr_src);

    // ---- text encoder (16 waves/block, 1 tile/wave, grid=256 -> 1 block/CU)
    k_gru_mfma<<<256, 1024, 0, stream>>>(xtext, embbf, w_ih, w_hh, b_ih, b_hh, ht);

    // ---- GCN layer 1
    k_mm1<<<(N_NODES + 3) / 4, 256, 0, stream>>>(x, ht, W1, dinv, ms);
    k_gather<<<(N_NODES + 3) / 4, 256, 0, stream>>>(ms, csr_src, starts, cnt, dinv, b1, h1);

    // ---- GCN layer 2
    k_mm64<<<(N_NODES + 3) / 4, 256, 0, stream>>>(h1, W2, dinv, ms);
    k_gather<<<(N_NODES + 3) / 4, 256, 0, stream>>>(ms, csr_src, starts, cnt, dinv, b2, h2);

    // ---- edge classifier
    k_edge_mfma<<<2048, 256, 0, stream>>>(ei, h2, Wl1, bl1, Wf, bf, out);
}

// Round 6
// 429.093 us; speedup vs baseline: 1.9046x; 1.9046x over previous
//
#include <hip/hip_runtime.h>
#include <math.h>

#define N_NODES 50000
#define N_EDGES 800000
#define SCAN_NB ((N_NODES + 255) / 256)   // 196
#define VOCAB   30000
#define NTILES  ((N_NODES + 31) / 32)     // 1563

typedef __attribute__((ext_vector_type(8)))  short bf16x8;
typedef __attribute__((ext_vector_type(4)))  float f32x4;
typedef __attribute__((ext_vector_type(16))) float f32x16;

__device__ inline short f2bf(float f) {
    union { float f; unsigned u; } v; v.f = f;
    unsigned r = v.u + 0x7FFFu + ((v.u >> 16) & 1u);   // RNE
    return (short)(r >> 16);
}

__device__ inline float fsig(float x)  { return __builtin_amdgcn_rcpf(1.0f + __expf(-x)); }
__device__ inline float ftanh(float x) { float t = __expf(2.0f * x); return 1.0f - 2.0f * __builtin_amdgcn_rcpf(t + 1.0f); }

__device__ inline f32x4 mfma16(bf16x8 a, bf16x8 b, f32x4 c) {
    return __builtin_amdgcn_mfma_f32_16x16x32_bf16(a, b, c, 0, 0, 0);
}
__device__ inline f32x16 mfma32(bf16x8 a, bf16x8 b, f32x16 c) {
    return __builtin_amdgcn_mfma_f32_32x32x16_bf16(a, b, c, 0, 0, 0);
}
__device__ inline f32x16 splat16(float v) {
    f32x16 r;
    #pragma unroll
    for (int i = 0; i < 16; ++i) r[i] = v;
    return r;
}

// ================================================================ embed -> bf16 table
__global__ void k_embcvt(const float* __restrict__ e, short* __restrict__ o) {
    int i = blockIdx.x * 256 + threadIdx.x;   // 8 elems per thread
    if (i >= VOCAB * 64 / 8) return;
    const float4* p = (const float4*)(e + i * 8);
    float4 a = p[0], b = p[1];
    bf16x8 v;
    v[0]=f2bf(a.x); v[1]=f2bf(a.y); v[2]=f2bf(a.z); v[3]=f2bf(a.w);
    v[4]=f2bf(b.x); v[5]=f2bf(b.y); v[6]=f2bf(b.z); v[7]=f2bf(b.w);
    *(bf16x8*)(o + i * 8) = v;
}

// ================================================================ CSR build
__global__ void k_count(const int* __restrict__ ei, int* __restrict__ cnt) {
    int e = blockIdx.x * 256 + threadIdx.x;
    if (e < N_EDGES) atomicAdd(&cnt[ei[N_EDGES + e]], 1);
}

__global__ void k_scan_local(const int* __restrict__ cnt, int* __restrict__ excl,
                             int* __restrict__ bsum) {
    __shared__ int s[256];
    int tid = threadIdx.x;
    int i = blockIdx.x * 256 + tid;
    int v = (i < N_NODES) ? cnt[i] : 0;
    s[tid] = v;
    __syncthreads();
    #pragma unroll
    for (int off = 1; off < 256; off <<= 1) {
        int t = (tid >= off) ? s[tid - off] : 0;
        __syncthreads();
        s[tid] += t;
        __syncthreads();
    }
    if (i < N_NODES) excl[i] = s[tid] - v;
    if (tid == 255) bsum[blockIdx.x] = s[255];
}

__global__ void k_scan_bsum(int* __restrict__ bsum) {
    __shared__ int s[256];
    int tid = threadIdx.x;
    int v = (tid < SCAN_NB) ? bsum[tid] : 0;
    s[tid] = v;
    __syncthreads();
    #pragma unroll
    for (int off = 1; off < 256; off <<= 1) {
        int t = (tid >= off) ? s[tid - off] : 0;
        __syncthreads();
        s[tid] += t;
        __syncthreads();
    }
    if (tid < SCAN_NB) bsum[tid] = s[tid] - v;
}

__global__ void k_make_starts(const int* __restrict__ excl, const int* __restrict__ bsum,
                              const int* __restrict__ cnt,
                              int* __restrict__ starts, int* __restrict__ cursor,
                              float* __restrict__ dinv) {
    int i = blockIdx.x * 256 + threadIdx.x;
    if (i >= N_NODES) return;
    int st = excl[i] + bsum[blockIdx.x];
    starts[i] = st;
    cursor[i] = st;
    dinv[i] = rsqrtf((float)cnt[i] + 1.0f);
}

__global__ void k_fill(const int* __restrict__ ei, int* __restrict__ cursor,
                       int* __restrict__ csr_src) {
    int e = blockIdx.x * 256 + threadIdx.x;
    if (e >= N_EDGES) return;
    int c = ei[N_EDGES + e];
    int p = atomicAdd(&cursor[c], 1);
    csr_src[p] = ei[e];
}

// ================================================================ GRU via 32x32x16 MFMA
// wave = 32 nodes (one tile). 1563 tiles, all waves resident in one round.
// A layout: row=lane&31, k = ks*16 + 8*(lane>>5) + i  (A and B use the SAME
// assumed k-map, so internal K permutations cancel).
// C/D layout (m74/m101): col=lane&31, row=(reg&3)+8*(reg>>2)+4*(lane>>5).
// Hidden dims split into 2 passes (r/z/n col-triples) to halve accumulators.
__global__ __launch_bounds__(256) void k_gru_mfma(
    const int*   __restrict__ xtext,
    const short* __restrict__ embbf,   // [VOCAB,64] bf16
    const float* __restrict__ w_ih, const float* __restrict__ w_hh,
    const float* __restrict__ b_ih, const float* __restrict__ b_hh,
    float* __restrict__ ht)            // [N,64]
{
    __shared__ short bfrag[2 * 4 * 6 * 64 * 8];   // [mat][ks][ct][lane][8] = 48KB
    __shared__ short hbuf[4][32 * 64];            // per-wave h, 16KB

    const int tid = threadIdx.x;
    // pack B-fragments: frag elem i = W[ct*32+(l&31)][ks*16+8*(l>>5)+i]
    for (int u = tid; u < 3072; u += 256) {
        int l   = u & 63;
        int ct  = (u >> 6) % 6;
        int ks  = (u / 384) % 4;
        int mat = u / 1536;
        const float* W = mat ? w_hh : w_ih;
        const float* src = &W[(ct * 32 + (l & 31)) * 64 + ks * 16 + ((l >> 5) << 3)];
        short* dst = &bfrag[u * 8];
        #pragma unroll
        for (int i = 0; i < 8; ++i) dst[i] = f2bf(src[i]);
    }
    __syncthreads();

    const int lane = tid & 63;
    const int wave = tid >> 6;
    const int l5 = lane >> 5;     // half
    const int cl = lane & 31;     // A-row / B,C-col

    const int tile  = blockIdx.x * 4 + wave;
    const int nbase = tile * 32;
    if (nbase >= N_NODES) return;

    // biases per pass p (dims j = p*32+cl): r/z combined ih+hh, n split
    float b_r[2], b_z[2], b_ni[2], b_nh[2];
    #pragma unroll
    for (int p = 0; p < 2; ++p) {
        int j = p * 32 + cl;
        b_r[p]  = b_ih[j]       + b_hh[j];
        b_z[p]  = b_ih[64 + j]  + b_hh[64 + j];
        b_ni[p] = b_ih[128 + j];
        b_nh[p] = b_hh[128 + j];
    }

    const bf16x8* BF = (const bf16x8*)bfrag;   // idx ((mat*4+ks)*6+ct)*64+lane
    short* hl = &hbuf[wave][0];

    float hr0[16], hr1[16];
    #pragma unroll
    for (int g = 0; g < 16; ++g) { hr0[g] = 0.0f; hr1[g] = 0.0f; }

    const int nclamp = min(nbase + cl, N_NODES - 1);
    const int* toks = &xtext[nclamp * 16];

    bf16x8 eA[4];
    {
        int tok = toks[0];
        const short* er = &embbf[tok * 64 + 8 * l5];
        eA[0] = *(const bf16x8*)(er);
        eA[1] = *(const bf16x8*)(er + 16);
        eA[2] = *(const bf16x8*)(er + 32);
        eA[3] = *(const bf16x8*)(er + 48);
    }

    for (int t = 0; t < 16; ++t) {
        // read h A-fragments (XOR-oct swizzled), shared by both passes
        bf16x8 hA[4];
        if (t > 0) {
            #pragma unroll
            for (int ks = 0; ks < 4; ++ks) {
                int o = (ks * 2 + l5) ^ (cl & 7);
                hA[ks] = *(const bf16x8*)&hl[cl * 64 + o * 8];
            }
        }

        // prefetch next-step embedding (hides HBM/L2 latency under MFMAs)
        bf16x8 eN[4];
        if (t < 15) {
            int tok = toks[t + 1];
            const short* er = &embbf[tok * 64 + 8 * l5];
            eN[0] = *(const bf16x8*)(er);
            eN[1] = *(const bf16x8*)(er + 16);
            eN[2] = *(const bf16x8*)(er + 32);
            eN[3] = *(const bf16x8*)(er + 48);
        }

        #pragma unroll
        for (int p = 0; p < 2; ++p) {
            f32x16 a_r  = splat16(b_r[p]);
            f32x16 a_z  = splat16(b_z[p]);
            f32x16 a_ni = splat16(b_ni[p]);
            f32x16 a_nh = splat16(b_nh[p]);

            // Gi
            #pragma unroll
            for (int ks = 0; ks < 4; ++ks) {
                a_r  = mfma32(eA[ks], BF[(ks * 6 + p) * 64 + lane], a_r);
                a_z  = mfma32(eA[ks], BF[(ks * 6 + 2 + p) * 64 + lane], a_z);
                a_ni = mfma32(eA[ks], BF[(ks * 6 + 4 + p) * 64 + lane], a_ni);
            }
            // Gh
            if (t > 0) {
                #pragma unroll
                for (int ks = 0; ks < 4; ++ks) {
                    a_r  = mfma32(hA[ks], BF[((4 + ks) * 6 + p) * 64 + lane], a_r);
                    a_z  = mfma32(hA[ks], BF[((4 + ks) * 6 + 2 + p) * 64 + lane], a_z);
                    a_nh = mfma32(hA[ks], BF[((4 + ks) * 6 + 4 + p) * 64 + lane], a_nh);
                }
            }

            // gates + h write (bf16, XOR-oct swizzle)
            float* hrp = p ? hr1 : hr0;
            const int j = p * 32 + cl;
            #pragma unroll
            for (int g = 0; g < 16; ++g) {
                float r  = fsig(a_r[g]);
                float z  = fsig(a_z[g]);
                float nn = ftanh(a_ni[g] + r * a_nh[g]);
                float h  = (1.0f - z) * nn + z * hrp[g];
                hrp[g] = h;
                int m = (g & 3) + 8 * (g >> 2) + 4 * l5;
                int o = (j >> 3) ^ (m & 7);
                hl[m * 64 + o * 8 + (j & 7)] = f2bf(h);
            }
        }

        #pragma unroll
        for (int i = 0; i < 4; ++i) eA[i] = eN[i];
    }

    // store ht [N,64]
    #pragma unroll
    for (int g = 0; g < 16; ++g) {
        int m = (g & 3) + 8 * (g >> 2) + 4 * l5;
        int n = nbase + m;
        if (n < N_NODES) {
            ht[n * 64 + cl]      = hr0[g];
            ht[n * 64 + 32 + cl] = hr1[g];
        }
    }
}

// ================================================================ dense ms = dinv*( [x|ht] @ W1 )
__global__ void k_mm1(const float* __restrict__ x, const float* __restrict__ ht,
                      const float* __restrict__ W, const float* __restrict__ dinv,
                      float* __restrict__ M) {
    __shared__ float Wl[72 * 64];
    int tid = threadIdx.x;
    for (int i = tid; i < 72 * 64; i += 256) Wl[i] = W[i];
    __syncthreads();
    int j = tid & 63;
    int n = blockIdx.x * 4 + (tid >> 6);
    if (n >= N_NODES) return;
    float acc = 0.0f;
    const float* xr = x + n * 8;
    #pragma unroll
    for (int k = 0; k < 8; ++k) acc += xr[k] * Wl[k * 64 + j];
    const float* hr = ht + n * 64;
    #pragma unroll
    for (int k = 0; k < 64; ++k) acc += hr[k] * Wl[(8 + k) * 64 + j];
    M[n * 64 + j] = dinv[n] * acc;
}

// ================================================================ dense ms = dinv*(X @ W)  (K=64)
__global__ void k_mm64(const float* __restrict__ X, const float* __restrict__ W,
                       const float* __restrict__ dinv, float* __restrict__ M) {
    __shared__ float Wl[64 * 64];
    int tid = threadIdx.x;
    for (int i = tid; i < 64 * 64; i += 256) Wl[i] = W[i];
    __syncthreads();
    int j = tid & 63;
    int n = blockIdx.x * 4 + (tid >> 6);
    if (n >= N_NODES) return;
    const float* xr = X + n * 64;
    float acc = 0.0f;
    #pragma unroll
    for (int k = 0; k < 64; ++k) acc += xr[k] * Wl[k * 64 + j];
    M[n * 64 + j] = dinv[n] * acc;
}

// ================================================================ gather + self + bias + relu
__global__ __launch_bounds__(256) void k_gather(
    const float* __restrict__ ms, const int* __restrict__ csr_src,
    const int* __restrict__ starts, const int* __restrict__ cnt,
    const float* __restrict__ dinv, const float* __restrict__ b,
    float* __restrict__ out)
{
    int n = blockIdx.x * 4 + (threadIdx.x >> 6);
    if (n >= N_NODES) return;
    int j = threadIdx.x & 63;
    int c = cnt[n];
    const int* lst = csr_src + starts[n];
    float acc = ms[n * 64 + j];   // self-loop term
    int k = 0;
    for (; k + 8 <= c; k += 8) {
        int r[8];
        #pragma unroll
        for (int u = 0; u < 8; ++u) r[u] = lst[k + u];
        #pragma unroll
        for (int u = 0; u < 8; ++u) acc += ms[r[u] * 64 + j];
    }
    for (; k < c; ++k) acc += ms[lst[k] * 64 + j];
    float v = dinv[n] * acc + b[j];
    out[n * 64 + j] = fmaxf(v, 0.0f);
}

// ================================================================ edge classifier via MFMA
__global__ __launch_bounds__(256) void k_edge_mfma(
    const int* __restrict__ ei, const float* __restrict__ h,
    const float* __restrict__ Wl1, const float* __restrict__ bl1,
    const float* __restrict__ Wf,  const float* __restrict__ bf,
    float* __restrict__ out)
{
    __shared__ float wl_s[128 * 64];
    const int tid = threadIdx.x;
    for (int i = tid; i < 128 * 64; i += 256) wl_s[i] = Wl1[i];
    __syncthreads();

    const int lane = tid & 63;
    const int wave = tid >> 6;
    const int lg = lane >> 4;
    const int ll = lane & 15;

    bf16x8 B[16];
    #pragma unroll
    for (int ks = 0; ks < 4; ++ks) {
        #pragma unroll
        for (int ct = 0; ct < 4; ++ct) {
            int c  = ct * 16 + ll;
            int kb = ks * 32 + 8 * lg;
            bf16x8 v;
            #pragma unroll
            for (int i = 0; i < 8; ++i) v[i] = f2bf(wl_s[(kb + i) * 64 + c]);
            B[ks * 4 + ct] = v;
        }
    }
    float wf0[4], wf1[4], bl[4];
    #pragma unroll
    for (int ct = 0; ct < 4; ++ct) {
        int c = ct * 16 + ll;
        wf0[ct] = Wf[c * 2 + 0];
        wf1[ct] = Wf[c * 2 + 1];
        bl[ct]  = bl1[c];
    }
    const float bf0 = bf[0], bf1 = bf[1];

    for (int tile = blockIdx.x * 4 + wave; tile < N_EDGES / 16; tile += gridDim.x * 4) {
        const int ebase = tile * 16;
        const int erow  = ebase + ll;
        const int src = ei[erow];
        const int dst = ei[N_EDGES + erow];

        f32x4 acc[4];
        #pragma unroll
        for (int ct = 0; ct < 4; ++ct) acc[ct] = (f32x4){bl[ct], bl[ct], bl[ct], bl[ct]};

        #pragma unroll
        for (int ks = 0; ks < 4; ++ks) {
            const int node = (ks < 2) ? src : dst;
            const float4* p = (const float4*)&h[node * 64 + (ks & 1) * 32 + 8 * lg];
            float4 a4 = p[0], b4 = p[1];
            float fa[8] = {a4.x, a4.y, a4.z, a4.w, b4.x, b4.y, b4.z, b4.w};
            bf16x8 A;
            #pragma unroll
            for (int i = 0; i < 8; ++i) A[i] = f2bf(fa[i]);
            #pragma unroll
            for (int ct = 0; ct < 4; ++ct) acc[ct] = mfma16(A, B[ks * 4 + ct], acc[ct]);
        }

        float p0[4], p1[4];
        #pragma unroll
        for (int q = 0; q < 4; ++q) { p0[q] = 0.0f; p1[q] = 0.0f; }
        #pragma unroll
        for (int ct = 0; ct < 4; ++ct) {
            #pragma unroll
            for (int q = 0; q < 4; ++q) {
                float hd = fmaxf(acc[ct][q], 0.0f);
                p0[q] += hd * wf0[ct];
                p1[q] += hd * wf1[ct];
            }
        }
        #pragma unroll
        for (int m = 1; m <= 8; m <<= 1) {
            #pragma unroll
            for (int q = 0; q < 4; ++q) {
                p0[q] += __shfl_xor(p0[q], m, 64);
                p1[q] += __shfl_xor(p1[q], m, 64);
            }
        }
        if (ll < 8) {
            int q = ll >> 1, cls = ll & 1;
            float l0 = p0[q] + bf0, l1 = p1[q] + bf1;
            float mx  = fmaxf(l0, l1);
            float lse = mx + __logf(__expf(l0 - mx) + __expf(l1 - mx));
            float val = (cls ? l1 : l0) - lse;
            out[(ebase + 4 * lg + q) * 2 + cls] = val;
        }
    }
}

// ================================================================ launch
extern "C" void kernel_launch(void* const* d_in, const int* in_sizes, int n_in,
                              void* d_out, int out_size, void* d_ws, size_t ws_size,
                              hipStream_t stream) {
    const float* x     = (const float*)d_in[0];
    const int*   ei    = (const int*)  d_in[1];
    const int*   xtext = (const int*)  d_in[2];
    const float* embed = (const float*)d_in[3];
    const float* w_ih  = (const float*)d_in[4];
    const float* w_hh  = (const float*)d_in[5];
    const float* b_ih  = (const float*)d_in[6];
    const float* b_hh  = (const float*)d_in[7];
    const float* W1    = (const float*)d_in[8];
    const float* b1    = (const float*)d_in[9];
    const float* W2    = (const float*)d_in[10];
    const float* b2    = (const float*)d_in[11];
    const float* Wl1   = (const float*)d_in[12];
    const float* bl1   = (const float*)d_in[13];
    const float* Wf    = (const float*)d_in[14];
    const float* bf    = (const float*)d_in[15];
    float* out = (float*)d_out;

    char* ws = (char*)d_ws;
    size_t off = 0;
    auto alloc = [&](size_t bytes) { char* p = ws + off; off += (bytes + 255) & ~size_t(255); return p; };
    float* ht      = (float*)alloc(N_NODES * 64 * 4);
    float* ms      = (float*)alloc(N_NODES * 64 * 4);
    float* h1      = (float*)alloc(N_NODES * 64 * 4);
    float* h2      = (float*)alloc(N_NODES * 64 * 4);
    float* dinv    = (float*)alloc(N_NODES * 4);
    int*   cnt     = (int*)  alloc(N_NODES * 4);
    int*   excl    = (int*)  alloc(N_NODES * 4);
    int*   starts  = (int*)  alloc(N_NODES * 4);
    int*   cursor  = (int*)  alloc(N_NODES * 4);
    int*   bsum    = (int*)  alloc(SCAN_NB * 4);
    int*   csr_src = (int*)  alloc(N_EDGES * 4);
    short* embbf   = (short*)alloc(VOCAB * 64 * 2);

    // ---- bf16 embedding table
    k_embcvt<<<(VOCAB * 64 / 8 + 255) / 256, 256, 0, stream>>>(embed, embbf);

    // ---- CSR build (shared by both GCN layers)
    hipMemsetAsync(cnt, 0, N_NODES * 4, stream);
    k_count<<<(N_EDGES + 255) / 256, 256, 0, stream>>>(ei, cnt);
    k_scan_local<<<SCAN_NB, 256, 0, stream>>>(cnt, excl, bsum);
    k_scan_bsum<<<1, 256, 0, stream>>>(bsum);
    k_make_starts<<<SCAN_NB, 256, 0, stream>>>(excl, bsum, cnt, starts, cursor, dinv);
    k_fill<<<(N_EDGES + 255) / 256, 256, 0, stream>>>(ei, cursor, csr_src);

    // ---- text encoder: 1563 tiles of 32 nodes, 4 waves/block -> 391 blocks,
    //      all waves resident in one round (no multi-tile tail)
    k_gru_mfma<<<(NTILES + 3) / 4, 256, 0, stream>>>(xtext, embbf, w_ih, w_hh, b_ih, b_hh, ht);

    // ---- GCN layer 1
    k_mm1<<<(N_NODES + 3) / 4, 256, 0, stream>>>(x, ht, W1, dinv, ms);
    k_gather<<<(N_NODES + 3) / 4, 256, 0, stream>>>(ms, csr_src, starts, cnt, dinv, b1, h1);

    // ---- GCN layer 2
    k_mm64<<<(N_NODES + 3) / 4, 256, 0, stream>>>(h1, W2, dinv, ms);
    k_gather<<<(N_NODES + 3) / 4, 256, 0, stream>>>(ms, csr_src, starts, cnt, dinv, b2, h2);

    // ---- edge classifier
    k_edge_mfma<<<2048, 256, 0, stream>>>(ei, h2, Wl1, bl1, Wf, bf, out);
}